// Round 11
// baseline (281.678 us; speedup 1.0000x reference)
//
#include <hip/hip_runtime.h>
#include <math.h>

// Problem constants
#define B_ 8
#define N_ 128
#define H_ 64
#define MH_ 128
#define D_ 4
#define TSTEPS 12
#define NBLK 512          // 2 blocks/CU x 256 CU -> all co-resident

typedef __attribute__((ext_vector_type(8))) short bf16x8;
typedef __attribute__((ext_vector_type(4))) float f32x4;
typedef __attribute__((ext_vector_type(4))) unsigned u32x4;
typedef unsigned uint32;

__device__ __forceinline__ float fast_tanh(float x) {
    float t = __builtin_amdgcn_exp2f(x * 2.8853900817779268f);
    return 1.0f - 2.0f * __builtin_amdgcn_rcpf(t + 1.0f);
}
__device__ __forceinline__ float fast_sigmoid(float x) {
    float t = __builtin_amdgcn_exp2f(x * -1.4426950408889634f);
    return __builtin_amdgcn_rcpf(1.0f + t);
}
__device__ __forceinline__ unsigned short f2bf(float x) {
    unsigned u = __builtin_bit_cast(unsigned, x);
    u += 0x7fffu + ((u >> 16) & 1u);   // RNE
    return (unsigned short)(u >> 16);
}
__device__ __forceinline__ uint32 pack2(float lo, float hi) {
    return (uint32)f2bf(lo) | ((uint32)f2bf(hi) << 16);
}

// ---------------- workspace layout (uint32 units) ----------------
// P(t+1) lives in its own per-step buffer (t = 0..10): consumer addresses are
// touched for the first time only after the producer's write-through lands, so
// plain coalesced loads are fresh without any fences. Producers publish via
// relaxed agent-scope (write-through) atomic stores.
// Sync is per (batch, i-window-of-32-rows): 32 counters, 64B apart.
constexpr int PB_STRIDE = 65536;              // [8][128][64] uints per step-buffer
constexpr int CTRLu = 11 * PB_STRIDE;         // cnt[8][4] @ stride 16; SSE @ +512; DONE @ +513
constexpr int CTRL_BYTES = (32 * 16 + 2) * 4;

__global__ __launch_bounds__(512, 4) void fused(
    const float* __restrict__ A, const float* __restrict__ X,
    const float* __restrict__ Wm1, const float* __restrict__ bm1,
    const float* __restrict__ Wm2, const float* __restrict__ bm2,
    const float* __restrict__ Wir, const float* __restrict__ bir,
    const float* __restrict__ Wii, const float* __restrict__ bii,
    const float* __restrict__ Win, const float* __restrict__ bin_,
    const float* __restrict__ Whr, const float* __restrict__ Whi, const float* __restrict__ Whh,
    const float* __restrict__ Wmr, const float* __restrict__ Wmi, const float* __restrict__ Wmn,
    const float* __restrict__ Wo1, const float* __restrict__ bo1,
    const float* __restrict__ Wo2, const float* __restrict__ bo2,
    const float* __restrict__ Wo3, const float* __restrict__ bo3,
    const float* __restrict__ lsg,
    uint32* wsU, float* __restrict__ out)
{
    __shared__ __align__(16) unsigned short wm2f[8192];  // 16 KB: Wm2 MFMA B-fragments
    __shared__ float Qj[2][128], apRow[2][128], rs[128], bmS[128];
    __shared__ float aggbuf[2][4][64];                   // also reused for rowsum partials
    __shared__ float sAgg[2][64], sAm[2][192];
    __shared__ float sH[2][64], sHn[2][64], sHP[2][192];
    __shared__ float sT1[2][64], sT2[2][64];
    __shared__ float sX[2][4], sTgt[2][4], sSq[2][4], sseb[2];

    const int bid = blockIdx.x, tid = threadIdx.x;
    const int b = bid >> 6;                 // batch
    const int j0 = (bid & 63) << 1;         // this block owns rows j0, j0+1
    const int jj = tid >> 8, tidj = tid & 255;
    const int jrow = j0 + jj;
    const int lane = tid & 63;
    const int wvj = (tid >> 6) & 3;         // wave index within the j-half
    const int l15 = lane & 15, g = lane >> 4;
    const int myI0 = wvj * 32;              // i-window base for this wave

    int*   cntBase = (int*)(wsU + CTRLu);
    int*   cntW    = cntBase + (b * 4 + wvj) * 16;          // window this wave CONSUMES
    int*   cntPub  = cntBase + (b * 4 + (j0 >> 5)) * 16;    // window this block PRODUCES
    float* sseG    = (float*)(wsU + CTRLu + 512);
    int*   doneG   = (int*)(wsU + CTRLu + 513);
    const float* Ab = A + b * 16384;

    // ================= init (fully block-local) =================
    {   // rowsum_i = sum_j sigmoid(0.5(A[i,j]+A[j,i])), j != i  (4-way split over j)
        int i = tid & 127, q = tid >> 7;
        float part = 0.f;
        int jlo = q * 32;
        #pragma unroll 8
        for (int j2 = jlo; j2 < jlo + 32; ++j2) {
            if (j2 != i)
                part += fast_sigmoid(0.5f * (Ab[i * 128 + j2] + Ab[j2 * 128 + i]));
        }
        ((float*)aggbuf)[q * 128 + i] = part;
    }
    __syncthreads();
    if (tid < 128) {
        const float* f = (const float*)aggbuf;
        rs[tid] = f[tid] + f[128 + tid] + f[256 + tid] + f[384 + tid] + 1e-6f;
        bmS[tid] = bm1[tid];
    }
    __syncthreads();
    if (tid < 256) {    // apRow[h][i] = s(i, j0+h) / rowsum_i
        int i = tid & 127, h = tid >> 7, jc = j0 + h;
        float s = (i == jc) ? 0.f
                : fast_sigmoid(0.5f * (Ab[i * 128 + jc] + Ab[jc * 128 + i]));
        apRow[h][i] = s / rs[i];
    }
    for (int idx = tid; idx < 8192; idx += 512) {   // pack Wm2 -> bf16 B-fragments
        int kt = idx >> 11, nt = (idx >> 9) & 3, ln = (idx >> 3) & 63, e = idx & 7;
        int k = kt * 32 + (ln >> 4) * 8 + e, n = nt * 16 + (ln & 15);
        wm2f[idx] = f2bf(Wm2[k * 64 + n]);
    }
    if (tidj < 128) Qj[jj][tidj] = 0.f;
    if (tidj < 64)  sH[jj][tidj] = 0.f;
    if (tidj < 192) sHP[jj][tidj] = 0.f;
    if (tid < 2) sseb[tid] = 0.f;
    __syncthreads();

    // ================= time loop =================
    for (int t = 0; t < TSTEPS; ++t) {
        const uint32* Psrc = wsU + (t - 1) * PB_STRIDE + b * 8192;  // valid for t>0
        if (t > 0) {
            // wave-level wait: only this wave's i-window needs to be published
            const int target = 64 * t;   // 16 blocks x 2 rows x 2 half-rows
            int guard = 0;
            while (__hip_atomic_load(cntW, __ATOMIC_RELAXED, __HIP_MEMORY_SCOPE_AGENT) < target
                   && guard < (1 << 20)) {
                __builtin_amdgcn_s_sleep(2);
                ++guard;
            }
            __builtin_amdgcn_fence(__ATOMIC_ACQUIRE, "workgroup");  // no hoisting of P loads
        }

        // ===== phase A: msg = tanh(tanh(P_i + Q_j) @ Wm2 + bm2), A-weighted agg =====
        f32x4 acc[2][4];
        #pragma unroll
        for (int mt = 0; mt < 2; ++mt)
            #pragma unroll
            for (int nt = 0; nt < 4; ++nt) {
                f32x4 z = {0.f, 0.f, 0.f, 0.f};
                acc[mt][nt] = z;
            }
        #pragma unroll
        for (int kt = 0; kt < 4; ++kt) {
            int k0 = kt * 32 + g * 8;
            bf16x8 bf[4];
            #pragma unroll
            for (int nt = 0; nt < 4; ++nt)
                bf[nt] = *(const bf16x8*)&wm2f[((kt * 4 + nt) * 64 + lane) << 3];
            f32x4 qa = *(const f32x4*)&Qj[jj][k0];
            f32x4 qb = *(const f32x4*)&Qj[jj][k0 + 4];
            bf16x8 af[2];
            #pragma unroll
            for (int mt = 0; mt < 2; ++mt) {
                int row = myI0 + mt * 16 + l15;
                float pe[8];
                if (t > 0) {    // direct 16B load from the fresh per-step buffer
                    u32x4 pv = *(const u32x4*)(Psrc + row * 64 + kt * 16 + g * 4);
                    #pragma unroll
                    for (int c = 0; c < 4; ++c) {
                        pe[2 * c]     = __builtin_bit_cast(float, pv[c] << 16);
                        pe[2 * c + 1] = __builtin_bit_cast(float, pv[c] & 0xFFFF0000u);
                    }
                } else {        // P(0) rows are all bm1 (h0 = 0)
                    #pragma unroll
                    for (int e = 0; e < 8; ++e) pe[e] = bmS[k0 + e];
                }
                #pragma unroll
                for (int e = 0; e < 4; ++e) {
                    af[mt][e]     = (short)f2bf(fast_tanh(pe[e] + qa[e]));
                    af[mt][4 + e] = (short)f2bf(fast_tanh(pe[4 + e] + qb[e]));
                }
            }
            #pragma unroll
            for (int mt = 0; mt < 2; ++mt)
                #pragma unroll
                for (int nt = 0; nt < 4; ++nt)
                    acc[mt][nt] = __builtin_amdgcn_mfma_f32_16x16x32_bf16(af[mt], bf[nt], acc[mt][nt], 0, 0, 0);
        }
        {
            float bmv[4];
            #pragma unroll
            for (int nt = 0; nt < 4; ++nt) bmv[nt] = bm2[nt * 16 + l15];
            float pagg[4] = {0.f, 0.f, 0.f, 0.f};
            #pragma unroll
            for (int mt = 0; mt < 2; ++mt) {
                float w[4];
                #pragma unroll
                for (int v = 0; v < 4; ++v) w[v] = apRow[jj][myI0 + mt * 16 + g * 4 + v];
                #pragma unroll
                for (int nt = 0; nt < 4; ++nt)
                    #pragma unroll
                    for (int v = 0; v < 4; ++v)
                        pagg[nt] += w[v] * fast_tanh(acc[mt][nt][v] + bmv[nt]);
            }
            #pragma unroll
            for (int nt = 0; nt < 4; ++nt) {
                pagg[nt] += __shfl_xor(pagg[nt], 16);
                pagg[nt] += __shfl_xor(pagg[nt], 32);
            }
            if (lane < 16)
                #pragma unroll
                for (int nt = 0; nt < 4; ++nt) aggbuf[jj][wvj][nt * 16 + lane] = pagg[nt];
        }
        __syncthreads();
        if (tidj < 64)
            sAgg[jj][tidj] = aggbuf[jj][0][tidj] + aggbuf[jj][1][tidj]
                           + aggbuf[jj][2][tidj] + aggbuf[jj][3][tidj];
        if (tidj < 4) {
            sX[jj][tidj]   = X[((b * 13 + t) * 128 + jrow) * 4 + tidj];
            sTgt[jj][tidj] = X[((b * 13 + t + 1) * 128 + jrow) * 4 + tidj];
        }
        __syncthreads();

        // ===== phase B (row-local; raw weights, L2-warm across the whole dispatch) =====
        if (tidj < 192) {   // am = agg @ [Wmr|Wmi|Wmn]
            const float* W = (tidj < 64) ? Wmr : (tidj < 128) ? Wmi : Wmn;
            int o = tidj & 63;
            float a = 0.f;
            #pragma unroll 8
            for (int k = 0; k < 64; ++k) a += sAgg[jj][k] * W[k * 64 + o];
            sAm[jj][tidj] = a;
        }
        __syncthreads();
        if (tidj < 64) {    // GRU gates
            int o = tidj;
            float xr = bir[o], xi = bii[o], xn = bin_[o];
            #pragma unroll
            for (int d = 0; d < 4; ++d) {
                float xv = sX[jj][d];
                xr += xv * Wir[d * 64 + o];
                xi += xv * Wii[d * 64 + o];
                xn += xv * Win[d * 64 + o];
            }
            float rr = fast_sigmoid(xr + sHP[jj][o]       + sAm[jj][o]);
            float ig = fast_sigmoid(xi + sHP[jj][64 + o]  + sAm[jj][64 + o]);
            float nn = fast_tanh  (xn + rr * sHP[jj][128 + o] + sAm[jj][128 + o]);
            float hn = (1.0f - ig) * nn + ig * sH[jj][o];
            sHn[jj][o] = hn;
            sH[jj][o]  = hn;
        }
        __syncthreads();

        if (t < TSTEPS - 1) {
            if (tidj < 128) {   // waves 0,1 / 4,5: P' -> publish -> signal (wave-local)
                int o = tidj;
                float a = bmS[o];
                #pragma unroll 8
                for (int k = 0; k < 64; ++k) a += sHn[jj][k] * Wm1[k * 128 + o];
                uint32 u = pack2(a, __shfl_down(a, 1));
                if ((o & 1) == 0) {
                    uint32* dst = wsU + t * PB_STRIDE + b * 8192 + jrow * 64 + (o >> 1);
                    __hip_atomic_store(dst, u, __ATOMIC_RELAXED, __HIP_MEMORY_SCOPE_AGENT);
                }
                asm volatile("s_waitcnt vmcnt(0)" ::: "memory");   // wave's stores landed
                if (lane == 0)
                    __hip_atomic_fetch_add(cntPub, 1, __ATOMIC_RELAXED, __HIP_MEMORY_SCOPE_AGENT);
            } else {            // waves 2,3 / 6,7: Q' (consumed locally next step)
                int oo = tidj - 128;
                float a = 0.f;
                #pragma unroll 8
                for (int k = 0; k < 64; ++k) a += sHn[jj][k] * Wm1[(64 + k) * 128 + oo];
                Qj[jj][oo] = a;
            }
            if (tidj < 192) {   // HP' = h @ [Whr|Whi|Whh]
                const float* W = (tidj < 64) ? Whr : (tidj < 128) ? Whi : Whh;
                int o = tidj & 63;
                float a = 0.f;
                #pragma unroll 8
                for (int k = 0; k < 64; ++k) a += sHn[jj][k] * W[k * 64 + o];
                sHP[jj][tidj] = a;
            }
        }

        // output MLP (off the inter-step critical path)
        if (tidj < 64) {
            float a = bo1[tidj];
            #pragma unroll 8
            for (int k = 0; k < 64; ++k) a += sHn[jj][k] * Wo1[k * 64 + tidj];
            sT1[jj][tidj] = fmaxf(a, 0.f);
        }
        __syncthreads();
        if (tidj < 64) {
            float a = bo2[tidj];
            #pragma unroll 8
            for (int k = 0; k < 64; ++k) a += sT1[jj][k] * Wo2[k * 64 + tidj];
            sT2[jj][tidj] = fmaxf(a, 0.f);
        }
        __syncthreads();
        if (tidj < 4) {
            float a = 0.f;
            #pragma unroll 8
            for (int k = 0; k < 64; ++k) a += sT2[jj][k] * Wo3[k * 4 + tidj];
            float p = sX[jj][tidj] + a + bo3[tidj];
            out[((b * TSTEPS + t) * 128 + jrow) * 4 + tidj] = p;
            float df = sTgt[jj][tidj] - p;
            sSq[jj][tidj] = df * df;
        }
        __syncthreads();
        if (tidj == 0)
            sseb[jj] += sSq[jj][0] + sSq[jj][1] + sSq[jj][2] + sSq[jj][3];
        __syncthreads();
    }

    // ================= finalize loglik (last-arriver) =================
    if (tid == 0) atomicAdd(sseG, sseb[0] + sseb[1]);
    __syncthreads();   // drain the SSE atomic before DONE
    if (tid == 0) {
        int prev = __hip_atomic_fetch_add(doneG, 1, __ATOMIC_RELAXED, __HIP_MEMORY_SCOPE_AGENT);
        if (prev == NBLK - 1) {
            float sse = __hip_atomic_load(sseG, __ATOMIC_RELAXED, __HIP_MEMORY_SCOPE_AGENT);
            float ls = lsg[0];
            float sigma = fminf(fmaxf(expf(ls), 1e-4f), 10.0f);
            float c = 0.5f * 4096.0f * logf(2.0f * 3.14159265358979323846f * sigma * sigma);
            float inv2s2 = 1.0f / (2.0f * sigma * sigma);
            out[B_ * TSTEPS * N_ * D_] = -(12.0f * c + sse * inv2s2);
        }
    }
}

extern "C" void kernel_launch(void* const* d_in, const int* in_sizes, int n_in,
                              void* d_out, int out_size, void* d_ws, size_t ws_size,
                              hipStream_t stream)
{
    const float* A    = (const float*)d_in[0];
    const float* X    = (const float*)d_in[1];
    const float* Wm1  = (const float*)d_in[2];
    const float* bm1  = (const float*)d_in[3];
    const float* Wm2  = (const float*)d_in[4];
    const float* bm2  = (const float*)d_in[5];
    const float* Wir  = (const float*)d_in[6];
    const float* bir  = (const float*)d_in[7];
    const float* Wii  = (const float*)d_in[8];
    const float* bii  = (const float*)d_in[9];
    const float* Win  = (const float*)d_in[10];
    const float* bin_ = (const float*)d_in[11];
    const float* Whr  = (const float*)d_in[12];
    const float* Whi  = (const float*)d_in[13];
    const float* Whh  = (const float*)d_in[14];
    const float* Wmr  = (const float*)d_in[15];
    const float* Wmi  = (const float*)d_in[16];
    const float* Wmn  = (const float*)d_in[17];
    const float* Wo1  = (const float*)d_in[18];
    const float* bo1  = (const float*)d_in[19];
    const float* Wo2  = (const float*)d_in[20];
    const float* bo2  = (const float*)d_in[21];
    const float* Wo3  = (const float*)d_in[22];
    const float* bo3  = (const float*)d_in[23];
    const float* lsg  = (const float*)d_in[24];
    uint32* wsU = (uint32*)d_ws;
    float* out = (float*)d_out;

    // zero counters / SSE / DONE each call (graph-replay safe)
    hipMemsetAsync((char*)d_ws + (size_t)CTRLu * 4, 0, CTRL_BYTES, stream);

    hipLaunchKernelGGL(fused, dim3(NBLK), dim3(512), 0, stream,
                       A, X, Wm1, bm1, Wm2, bm2, Wir, bir, Wii, bii, Win, bin_,
                       Whr, Whi, Whh, Wmr, Wmi, Wmn, Wo1, bo1, Wo2, bo2, Wo3, bo3,
                       lsg, wsU, out);
}

// Round 13
// 254.885 us; speedup vs baseline: 1.1051x; 1.1051x over previous
//
#include <hip/hip_runtime.h>
#include <math.h>

// Problem constants
#define B_ 8
#define N_ 128
#define H_ 64
#define MH_ 128
#define D_ 4
#define TSTEPS 12
#define NBLK 512          // 2 blocks/CU x 256 CU -> all co-resident

typedef __attribute__((ext_vector_type(8))) short bf16x8;
typedef __attribute__((ext_vector_type(4))) float f32x4;
typedef __attribute__((ext_vector_type(4))) unsigned u32x4;
typedef unsigned uint32;

__device__ __forceinline__ float fast_tanh(float x) {
    float t = __builtin_amdgcn_exp2f(x * 2.8853900817779268f);
    return 1.0f - 2.0f * __builtin_amdgcn_rcpf(t + 1.0f);
}
__device__ __forceinline__ float fast_sigmoid(float x) {
    float t = __builtin_amdgcn_exp2f(x * -1.4426950408889634f);
    return __builtin_amdgcn_rcpf(1.0f + t);
}
__device__ __forceinline__ unsigned short f2bf(float x) {
    unsigned u = __builtin_bit_cast(unsigned, x);
    u += 0x7fffu + ((u >> 16) & 1u);   // RNE
    return (unsigned short)(u >> 16);
}
// packed bf16 pair: low16 = bf16(lo), high16 = bf16(hi); RNE (same as f2bf)
__device__ __forceinline__ uint32 cvtpk(float lo, float hi) {
    uint32 r;
    asm("v_cvt_pk_bf16_f32 %0, %1, %2" : "=v"(r) : "v"(lo), "v"(hi));
    return r;
}

// ---------------- workspace layout (uint32 units) ----------------
// P(t+1) lives in its own per-step buffer (t = 0..10): consumer addresses are
// touched for the first time only after the producer's write-through lands, so
// plain coalesced loads are fresh without any fences. Producers publish via
// relaxed agent-scope (write-through) atomic stores.
// Sync is per (batch, i-window-of-32-rows): 32 counters, 64B apart.
constexpr int PB_STRIDE = 65536;              // [8][128][64] uints per step-buffer
constexpr int CTRLu = 11 * PB_STRIDE;         // cnt[8][4] @ stride 16; SSE @ +512; DONE @ +513
constexpr int CTRL_BYTES = (32 * 16 + 2) * 4;

__global__ __launch_bounds__(512, 4) void fused(
    const float* __restrict__ A, const float* __restrict__ X,
    const float* __restrict__ Wm1, const float* __restrict__ bm1,
    const float* __restrict__ Wm2, const float* __restrict__ bm2,
    const float* __restrict__ Wir, const float* __restrict__ bir,
    const float* __restrict__ Wii, const float* __restrict__ bii,
    const float* __restrict__ Win, const float* __restrict__ bin_,
    const float* __restrict__ Whr, const float* __restrict__ Whi, const float* __restrict__ Whh,
    const float* __restrict__ Wmr, const float* __restrict__ Wmi, const float* __restrict__ Wmn,
    const float* __restrict__ Wo1, const float* __restrict__ bo1,
    const float* __restrict__ Wo2, const float* __restrict__ bo2,
    const float* __restrict__ Wo3, const float* __restrict__ bo3,
    const float* __restrict__ lsg,
    uint32* wsU, float* __restrict__ out)
{
    __shared__ __align__(16) unsigned short wm2f[8192];  // 16 KB: Wm2 MFMA B-fragments
    __shared__ float Qj[2][128], apRow[2][128], rs[128], bmS[128];
    __shared__ float aggbuf[2][4][64];                   // also reused for rowsum partials
    __shared__ float sAgg[2][64], sAm[2][192];
    __shared__ float sH[2][64], sHn[2][64], sHP[2][192];
    __shared__ float sT1[2][64], sT2[2][64];
    __shared__ float sX[2][4], sTgt[2][4], sSq[2][4], sseb[1];

    const int bid = blockIdx.x, tid = threadIdx.x;
    const int b = bid >> 6;                 // batch
    const int j0 = (bid & 63) << 1;         // this block owns rows j0, j0+1
    const int jj = tid >> 8, tidj = tid & 255;
    const int jrow = j0 + jj;
    const int lane = tid & 63;
    const int wvj = (tid >> 6) & 3;         // wave index within the j-half
    const int l15 = lane & 15, g = lane >> 4;
    const int myI0 = wvj * 32;              // i-window base for this wave

    int*   cntBase = (int*)(wsU + CTRLu);
    int*   cntW    = cntBase + (b * 4 + wvj) * 16;          // window this wave CONSUMES
    int*   cntPub  = cntBase + (b * 4 + (j0 >> 5)) * 16;    // window this block PRODUCES
    float* sseG    = (float*)(wsU + CTRLu + 512);
    int*   doneG   = (int*)(wsU + CTRLu + 513);
    const float* Ab = A + b * 16384;

    // ================= init (fully block-local) =================
    {   // rowsum_i = sum_j sigmoid(0.5(A[i,j]+A[j,i])), j != i  (4-way split over j)
        int i = tid & 127, q = tid >> 7;
        float part = 0.f;
        int jlo = q * 32;
        #pragma unroll 8
        for (int j2 = jlo; j2 < jlo + 32; ++j2) {
            if (j2 != i)
                part += fast_sigmoid(0.5f * (Ab[i * 128 + j2] + Ab[j2 * 128 + i]));
        }
        ((float*)aggbuf)[q * 128 + i] = part;
    }
    __syncthreads();
    if (tid < 128) {
        const float* f = (const float*)aggbuf;
        rs[tid] = f[tid] + f[128 + tid] + f[256 + tid] + f[384 + tid] + 1e-6f;
        bmS[tid] = bm1[tid];
    }
    __syncthreads();
    if (tid < 256) {    // apRow[h][i] = s(i, j0+h) / rowsum_i
        int i = tid & 127, h = tid >> 7, jc = j0 + h;
        float s = (i == jc) ? 0.f
                : fast_sigmoid(0.5f * (Ab[i * 128 + jc] + Ab[jc * 128 + i]));
        apRow[h][i] = s / rs[i];
    }
    for (int idx = tid; idx < 8192; idx += 512) {   // pack Wm2 -> bf16 B-fragments
        int kt = idx >> 11, nt = (idx >> 9) & 3, ln = (idx >> 3) & 63, e = idx & 7;
        int k = kt * 32 + (ln >> 4) * 8 + e, n = nt * 16 + (ln & 15);
        wm2f[idx] = f2bf(Wm2[k * 64 + n]);
    }
    if (tidj < 128) Qj[jj][tidj] = 0.f;
    if (tidj < 64)  sH[jj][tidj] = 0.f;
    if (tidj < 192) sHP[jj][tidj] = 0.f;
    if (tid == 0) sseb[0] = 0.f;
    __syncthreads();

    // ================= time loop =================
    for (int t = 0; t < TSTEPS; ++t) {
        const uint32* Psrc = wsU + (t - 1) * PB_STRIDE + b * 8192;  // valid for t>0
        if (t > 0) {
            // wave-level wait: only this wave's i-window needs to be published
            const int target = 32 * t;   // 16 blocks x 2 publisher-waves
            int guard = 0;
            while (__hip_atomic_load(cntW, __ATOMIC_RELAXED, __HIP_MEMORY_SCOPE_AGENT) < target
                   && guard < (1 << 20)) {
                __builtin_amdgcn_s_sleep(1);
                ++guard;
            }
            __builtin_amdgcn_fence(__ATOMIC_ACQUIRE, "workgroup");  // no hoisting of P loads
        }

        // ===== phase A: msg = tanh(tanh(P_i + Q_j) @ Wm2 + bm2), A-weighted agg =====
        f32x4 acc[2][4];
        #pragma unroll
        for (int mt = 0; mt < 2; ++mt)
            #pragma unroll
            for (int nt = 0; nt < 4; ++nt) {
                f32x4 z = {0.f, 0.f, 0.f, 0.f};
                acc[mt][nt] = z;
            }
        #pragma unroll
        for (int kt = 0; kt < 4; ++kt) {
            int k0 = kt * 32 + g * 8;
            bf16x8 bf[4];
            #pragma unroll
            for (int nt = 0; nt < 4; ++nt)
                bf[nt] = *(const bf16x8*)&wm2f[((kt * 4 + nt) * 64 + lane) << 3];
            f32x4 qa = *(const f32x4*)&Qj[jj][k0];
            f32x4 qb = *(const f32x4*)&Qj[jj][k0 + 4];
            bf16x8 af[2];
            #pragma unroll
            for (int mt = 0; mt < 2; ++mt) {
                int row = myI0 + mt * 16 + l15;
                float pe[8];
                if (t > 0) {    // direct 16B load from the fresh per-step buffer
                    u32x4 pv = *(const u32x4*)(Psrc + row * 64 + kt * 16 + g * 4);
                    #pragma unroll
                    for (int c = 0; c < 4; ++c) {
                        pe[2 * c]     = __builtin_bit_cast(float, pv[c] << 16);
                        pe[2 * c + 1] = __builtin_bit_cast(float, pv[c] & 0xFFFF0000u);
                    }
                } else {        // P(0) rows are all bm1 (h0 = 0)
                    #pragma unroll
                    for (int e = 0; e < 8; ++e) pe[e] = bmS[k0 + e];
                }
                float tv[8];
                #pragma unroll
                for (int e = 0; e < 4; ++e) {
                    tv[e]     = fast_tanh(pe[e] + qa[e]);
                    tv[4 + e] = fast_tanh(pe[4 + e] + qb[e]);
                }
                u32x4 aw;
                aw[0] = cvtpk(tv[0], tv[1]); aw[1] = cvtpk(tv[2], tv[3]);
                aw[2] = cvtpk(tv[4], tv[5]); aw[3] = cvtpk(tv[6], tv[7]);
                af[mt] = __builtin_bit_cast(bf16x8, aw);
            }
            #pragma unroll
            for (int mt = 0; mt < 2; ++mt)
                #pragma unroll
                for (int nt = 0; nt < 4; ++nt)
                    acc[mt][nt] = __builtin_amdgcn_mfma_f32_16x16x32_bf16(af[mt], bf[nt], acc[mt][nt], 0, 0, 0);
        }
        {
            float bmv[4];
            #pragma unroll
            for (int nt = 0; nt < 4; ++nt) bmv[nt] = bm2[nt * 16 + l15];
            float pagg[4] = {0.f, 0.f, 0.f, 0.f};
            #pragma unroll
            for (int mt = 0; mt < 2; ++mt) {
                float w[4];
                #pragma unroll
                for (int v = 0; v < 4; ++v) w[v] = apRow[jj][myI0 + mt * 16 + g * 4 + v];
                #pragma unroll
                for (int nt = 0; nt < 4; ++nt)
                    #pragma unroll
                    for (int v = 0; v < 4; ++v)
                        pagg[nt] += w[v] * fast_tanh(acc[mt][nt][v] + bmv[nt]);
            }
            #pragma unroll
            for (int nt = 0; nt < 4; ++nt) {
                pagg[nt] += __shfl_xor(pagg[nt], 16);
                pagg[nt] += __shfl_xor(pagg[nt], 32);
            }
            if (lane < 16)
                #pragma unroll
                for (int nt = 0; nt < 4; ++nt) aggbuf[jj][wvj][nt * 16 + lane] = pagg[nt];
        }
        __syncthreads();
        if (tidj < 64)
            sAgg[jj][tidj] = aggbuf[jj][0][tidj] + aggbuf[jj][1][tidj]
                           + aggbuf[jj][2][tidj] + aggbuf[jj][3][tidj];
        if (tidj < 4) {
            sX[jj][tidj]   = X[((b * 13 + t) * 128 + jrow) * 4 + tidj];
            sTgt[jj][tidj] = X[((b * 13 + t + 1) * 128 + jrow) * 4 + tidj];
        }
        __syncthreads();

        // ===== phase B (threads 0-255 only; 2-row accumulators halve weight traffic) =====
        if (tid < 192) {   // am = agg @ [Wmr|Wmi|Wmn], both rows
            const float* W = (tid < 64) ? Wmr : (tid < 128) ? Wmi : Wmn;
            int oc = tid & 63;
            float a0 = 0.f, a1 = 0.f;
            #pragma unroll 8
            for (int k = 0; k < 64; ++k) {
                float w = W[k * 64 + oc];
                a0 += sAgg[0][k] * w;
                a1 += sAgg[1][k] * w;
            }
            sAm[0][tid] = a0; sAm[1][tid] = a1;
        }
        __syncthreads();
        if (tid < 64) {    // GRU gates, both rows (x-weight columns read once)
            int o = tid;
            float xr0 = bir[o], xi0 = bii[o], xn0 = bin_[o];
            float xr1 = xr0, xi1 = xi0, xn1 = xn0;
            #pragma unroll
            for (int d = 0; d < 4; ++d) {
                float w1 = Wir[d * 64 + o], w2 = Wii[d * 64 + o], w3 = Win[d * 64 + o];
                xr0 += sX[0][d] * w1; xr1 += sX[1][d] * w1;
                xi0 += sX[0][d] * w2; xi1 += sX[1][d] * w2;
                xn0 += sX[0][d] * w3; xn1 += sX[1][d] * w3;
            }
            {
                float rr = fast_sigmoid(xr0 + sHP[0][o]       + sAm[0][o]);
                float ig = fast_sigmoid(xi0 + sHP[0][64 + o]  + sAm[0][64 + o]);
                float nn = fast_tanh  (xn0 + rr * sHP[0][128 + o] + sAm[0][128 + o]);
                float hn = (1.0f - ig) * nn + ig * sH[0][o];
                sHn[0][o] = hn; sH[0][o] = hn;
            }
            {
                float rr = fast_sigmoid(xr1 + sHP[1][o]       + sAm[1][o]);
                float ig = fast_sigmoid(xi1 + sHP[1][64 + o]  + sAm[1][64 + o]);
                float nn = fast_tanh  (xn1 + rr * sHP[1][128 + o] + sAm[1][128 + o]);
                float hn = (1.0f - ig) * nn + ig * sH[1][o];
                sHn[1][o] = hn; sH[1][o] = hn;
            }
        }
        __syncthreads();

        if (t < TSTEPS - 1) {
            if (tid < 128) {        // waves 0,1: P' both rows -> publish -> signal
                int o = tid;
                float a0 = bmS[o], a1 = a0;
                #pragma unroll 8
                for (int k = 0; k < 64; ++k) {
                    float w = Wm1[k * 128 + o];
                    a0 += sHn[0][k] * w; a1 += sHn[1][k] * w;
                }
                uint32 u0 = cvtpk(a0, __shfl_down(a0, 1));
                uint32 u1 = cvtpk(a1, __shfl_down(a1, 1));
                if ((o & 1) == 0) {
                    uint32* base = wsU + t * PB_STRIDE + b * 8192;
                    __hip_atomic_store(base + j0 * 64 + (o >> 1),       u0,
                                       __ATOMIC_RELAXED, __HIP_MEMORY_SCOPE_AGENT);
                    __hip_atomic_store(base + (j0 + 1) * 64 + (o >> 1), u1,
                                       __ATOMIC_RELAXED, __HIP_MEMORY_SCOPE_AGENT);
                }
                asm volatile("s_waitcnt vmcnt(0)" ::: "memory");   // wave's stores landed
                if (lane == 0)
                    __hip_atomic_fetch_add(cntPub, 1, __ATOMIC_RELAXED, __HIP_MEMORY_SCOPE_AGENT);
            } else if (tid < 256) { // waves 2,3: Q' both rows (consumed locally next step)
                int oo = tid - 128;
                float a0 = 0.f, a1 = 0.f;
                #pragma unroll 8
                for (int k = 0; k < 64; ++k) {
                    float w = Wm1[(64 + k) * 128 + oo];
                    a0 += sHn[0][k] * w; a1 += sHn[1][k] * w;
                }
                Qj[0][oo] = a0; Qj[1][oo] = a1;
            }
            if (tid < 192) {        // HP' = h @ [Whr|Whi|Whh], both rows
                const float* W = (tid < 64) ? Whr : (tid < 128) ? Whi : Whh;
                int oc = tid & 63;
                float a0 = 0.f, a1 = 0.f;
                #pragma unroll 8
                for (int k = 0; k < 64; ++k) {
                    float w = W[k * 64 + oc];
                    a0 += sHn[0][k] * w; a1 += sHn[1][k] * w;
                }
                sHP[0][tid] = a0; sHP[1][tid] = a1;
            }
        }

        // output MLP, both rows (off the inter-step critical path)
        if (tid < 64) {
            float a0 = bo1[tid], a1 = a0;
            #pragma unroll 8
            for (int k = 0; k < 64; ++k) {
                float w = Wo1[k * 64 + tid];
                a0 += sHn[0][k] * w; a1 += sHn[1][k] * w;
            }
            sT1[0][tid] = fmaxf(a0, 0.f); sT1[1][tid] = fmaxf(a1, 0.f);
        }
        __syncthreads();
        if (tid < 64) {
            float a0 = bo2[tid], a1 = a0;
            #pragma unroll 8
            for (int k = 0; k < 64; ++k) {
                float w = Wo2[k * 64 + tid];
                a0 += sT1[0][k] * w; a1 += sT1[1][k] * w;
            }
            sT2[0][tid] = fmaxf(a0, 0.f); sT2[1][tid] = fmaxf(a1, 0.f);
        }
        __syncthreads();
        if (tid < 4) {
            float a0 = 0.f, a1 = 0.f;
            #pragma unroll 8
            for (int k = 0; k < 64; ++k) {
                float w = Wo3[k * 4 + tid];
                a0 += sT2[0][k] * w; a1 += sT2[1][k] * w;
            }
            float p0 = sX[0][tid] + a0 + bo3[tid];
            float p1 = sX[1][tid] + a1 + bo3[tid];
            out[((b * TSTEPS + t) * 128 + j0) * 4 + tid]       = p0;
            out[((b * TSTEPS + t) * 128 + j0 + 1) * 4 + tid]   = p1;
            float d0 = sTgt[0][tid] - p0, d1 = sTgt[1][tid] - p1;
            sSq[0][tid] = d0 * d0; sSq[1][tid] = d1 * d1;
        }
        __syncthreads();
        if (tid == 0)
            sseb[0] += sSq[0][0] + sSq[0][1] + sSq[0][2] + sSq[0][3]
                     + sSq[1][0] + sSq[1][1] + sSq[1][2] + sSq[1][3];
        __syncthreads();
    }

    // ================= finalize loglik (last-arriver) =================
    if (tid == 0) atomicAdd(sseG, sseb[0]);
    __syncthreads();   // drain the SSE atomic before DONE
    if (tid == 0) {
        int prev = __hip_atomic_fetch_add(doneG, 1, __ATOMIC_RELAXED, __HIP_MEMORY_SCOPE_AGENT);
        if (prev == NBLK - 1) {
            float sse = __hip_atomic_load(sseG, __ATOMIC_RELAXED, __HIP_MEMORY_SCOPE_AGENT);
            float ls = lsg[0];
            float sigma = fminf(fmaxf(expf(ls), 1e-4f), 10.0f);
            float c = 0.5f * 4096.0f * logf(2.0f * 3.14159265358979323846f * sigma * sigma);
            float inv2s2 = 1.0f / (2.0f * sigma * sigma);
            out[B_ * TSTEPS * N_ * D_] = -(12.0f * c + sse * inv2s2);
        }
    }
}

extern "C" void kernel_launch(void* const* d_in, const int* in_sizes, int n_in,
                              void* d_out, int out_size, void* d_ws, size_t ws_size,
                              hipStream_t stream)
{
    const float* A    = (const float*)d_in[0];
    const float* X    = (const float*)d_in[1];
    const float* Wm1  = (const float*)d_in[2];
    const float* bm1  = (const float*)d_in[3];
    const float* Wm2  = (const float*)d_in[4];
    const float* bm2  = (const float*)d_in[5];
    const float* Wir  = (const float*)d_in[6];
    const float* bir  = (const float*)d_in[7];
    const float* Wii  = (const float*)d_in[8];
    const float* bii  = (const float*)d_in[9];
    const float* Win  = (const float*)d_in[10];
    const float* bin_ = (const float*)d_in[11];
    const float* Whr  = (const float*)d_in[12];
    const float* Whi  = (const float*)d_in[13];
    const float* Whh  = (const float*)d_in[14];
    const float* Wmr  = (const float*)d_in[15];
    const float* Wmi  = (const float*)d_in[16];
    const float* Wmn  = (const float*)d_in[17];
    const float* Wo1  = (const float*)d_in[18];
    const float* bo1  = (const float*)d_in[19];
    const float* Wo2  = (const float*)d_in[20];
    const float* bo2  = (const float*)d_in[21];
    const float* Wo3  = (const float*)d_in[22];
    const float* bo3  = (const float*)d_in[23];
    const float* lsg  = (const float*)d_in[24];
    uint32* wsU = (uint32*)d_ws;
    float* out = (float*)d_out;

    // zero counters / SSE / DONE each call (graph-replay safe)
    hipMemsetAsync((char*)d_ws + (size_t)CTRLu * 4, 0, CTRL_BYTES, stream);

    hipLaunchKernelGGL(fused, dim3(NBLK), dim3(512), 0, stream,
                       A, X, Wm1, bm1, Wm2, bm2, Wir, bir, Wii, bii, Win, bin_,
                       Whr, Whi, Whh, Wmr, Wmi, Wmn, Wo1, bo1, Wo2, bo2, Wo3, bo3,
                       lsg, wsU, out);
}

// Round 14
// 219.874 us; speedup vs baseline: 1.2811x; 1.1592x over previous
//
#include <hip/hip_runtime.h>
#include <math.h>

// Problem constants
#define B_ 8
#define N_ 128
#define H_ 64
#define MH_ 128
#define D_ 4
#define TSTEPS 12
#define NBLK 256          // 1 block/CU x 256 CU -> all co-resident

typedef __attribute__((ext_vector_type(8))) short bf16x8;
typedef __attribute__((ext_vector_type(4))) float f32x4;
typedef __attribute__((ext_vector_type(4))) unsigned u32x4;
typedef unsigned uint32;

__device__ __forceinline__ float fast_tanh(float x) {
    float t = __builtin_amdgcn_exp2f(x * 2.8853900817779268f);
    return 1.0f - 2.0f * __builtin_amdgcn_rcpf(t + 1.0f);
}
__device__ __forceinline__ float fast_sigmoid(float x) {
    float t = __builtin_amdgcn_exp2f(x * -1.4426950408889634f);
    return __builtin_amdgcn_rcpf(1.0f + t);
}
__device__ __forceinline__ unsigned short f2bf(float x) {
    unsigned u = __builtin_bit_cast(unsigned, x);
    u += 0x7fffu + ((u >> 16) & 1u);   // RNE
    return (unsigned short)(u >> 16);
}
// packed bf16 pair: low16 = bf16(lo), high16 = bf16(hi); RNE (same as f2bf)
__device__ __forceinline__ uint32 cvtpk(float lo, float hi) {
    uint32 r;
    asm("v_cvt_pk_bf16_f32 %0, %1, %2" : "=v"(r) : "v"(lo), "v"(hi));
    return r;
}

// ---------------- workspace layout (uint32 units) ----------------
// P(t+1) in its own per-step buffer (t = 0..10): consumer addresses are first
// touched only after the producer's write-through lands -> plain coalesced
// loads are fresh, no fences. Producers publish via relaxed agent-scope
// (write-through) atomic stores. Sync per (batch, 32-row i-window).
constexpr int PB_STRIDE = 65536;              // [8][128][64] uints per step-buffer
constexpr int CTRLu = 11 * PB_STRIDE;         // cnt[8][4] @ stride 16; SSE @ +512; DONE @ +513
constexpr int CTRL_BYTES = (32 * 16 + 2) * 4;

__global__ __launch_bounds__(1024, 4) void fused(
    const float* __restrict__ A, const float* __restrict__ X,
    const float* __restrict__ Wm1, const float* __restrict__ bm1,
    const float* __restrict__ Wm2, const float* __restrict__ bm2,
    const float* __restrict__ Wir, const float* __restrict__ bir,
    const float* __restrict__ Wii, const float* __restrict__ bii,
    const float* __restrict__ Win, const float* __restrict__ bin_,
    const float* __restrict__ Whr, const float* __restrict__ Whi, const float* __restrict__ Whh,
    const float* __restrict__ Wmr, const float* __restrict__ Wmi, const float* __restrict__ Wmn,
    const float* __restrict__ Wo1, const float* __restrict__ bo1,
    const float* __restrict__ Wo2, const float* __restrict__ bo2,
    const float* __restrict__ Wo3, const float* __restrict__ bo3,
    const float* __restrict__ lsg,
    uint32* wsU, float* __restrict__ out)
{
    __shared__ __align__(16) unsigned short wm2f[8192];  // 16 KB Wm2 MFMA B-fragments
    __shared__ __align__(16) float WamL[12288];          // 48 KB [k][192] Wmr|Wmi|Wmn
    __shared__ __align__(16) float Wm1L[16384];          // 64 KB [k][128] (full Wm1)
    __shared__ float Qj[4][128], apRow[4][128], rs[128], bmS[128];
    __shared__ float aggbuf[4][4][64];                   // reused for rowsum partials at init
    __shared__ float sAgg[4][64], sAm[4][192];
    __shared__ float sH[4][64], sHn[4][64], sHP[4][192];
    __shared__ float sT1[4][64], sT2[4][64];
    __shared__ float sX[4][4], sTgt[4][4], sSq[4][4], sseb[1];

    const int bid = blockIdx.x, tid = threadIdx.x;
    const int b = bid >> 5;                 // batch
    const int j0 = (bid & 31) << 2;         // block owns rows j0..j0+3
    const int wave = tid >> 6, lane = tid & 63;
    const int jj = wave >> 2;               // which of the 4 j-rows (phase A)
    const int wvj = wave & 3;               // i-window index (phase A)
    const int l15 = lane & 15, g = lane >> 4;
    const int myI0 = wvj * 32;

    int*   cntBase = (int*)(wsU + CTRLu);
    int*   cntW    = cntBase + (b * 4 + wvj) * 16;          // window this wave CONSUMES
    int*   cntPub  = cntBase + (b * 4 + (j0 >> 5)) * 16;    // window this block PRODUCES
    float* sseG    = (float*)(wsU + CTRLu + 512);
    int*   doneG   = (int*)(wsU + CTRLu + 513);
    const float* Ab = A + b * 16384;

    // ================= init (fully block-local) =================
    {   // rowsum_i: 1024 threads, 8 chunks of 16 j each
        int i = tid & 127, q = tid >> 7;
        float part = 0.f;
        int jlo = q * 16;
        #pragma unroll 4
        for (int j2 = jlo; j2 < jlo + 16; ++j2)
            if (j2 != i)
                part += fast_sigmoid(0.5f * (Ab[i * 128 + j2] + Ab[j2 * 128 + i]));
        ((float*)aggbuf)[q * 128 + i] = part;   // [8][128] view (1024 floats)
    }
    __syncthreads();
    if (tid < 128) {
        const float* f = (const float*)aggbuf;
        float s = 0.f;
        #pragma unroll
        for (int c = 0; c < 8; ++c) s += f[c * 128 + tid];
        rs[tid] = s + 1e-6f;
        bmS[tid] = bm1[tid];
    }
    __syncthreads();
    if (tid < 512) {    // apRow[h][i] = s(i, j0+h) / rowsum_i
        int i = tid & 127, h = tid >> 7, jc = j0 + h;
        float s = (i == jc) ? 0.f
                : fast_sigmoid(0.5f * (Ab[i * 128 + jc] + Ab[jc * 128 + i]));
        apRow[h][i] = s / rs[i];
    }
    for (int idx = tid; idx < 8192; idx += 1024) {   // pack Wm2 -> bf16 B-fragments
        int kt = idx >> 11, nt = (idx >> 9) & 3, ln = (idx >> 3) & 63, e = idx & 7;
        int k = kt * 32 + (ln >> 4) * 8 + e, n = nt * 16 + (ln & 15);
        wm2f[idx] = f2bf(Wm2[k * 64 + n]);
    }
    for (int idx = tid; idx < 12288; idx += 1024) {  // WamL[k*192+c] fp32
        int k = idx / 192, c = idx % 192;
        WamL[idx] = ((c < 64) ? Wmr : (c < 128) ? Wmi : Wmn)[k * 64 + (c & 63)];
    }
    for (int idx = tid; idx < 16384; idx += 1024)    // Wm1L direct copy [128][128]
        Wm1L[idx] = Wm1[idx];
    if (tid < 512) Qj[tid >> 7][tid & 127] = 0.f;
    if (tid < 256) sH[tid >> 6][tid & 63] = 0.f;
    if (tid < 768) sHP[tid / 192][tid % 192] = 0.f;
    if (tid == 0) sseb[0] = 0.f;
    __syncthreads();

    // ================= time loop =================
    for (int t = 0; t < TSTEPS; ++t) {
        const uint32* Psrc = wsU + (t - 1) * PB_STRIDE + b * 8192;  // valid for t>0
        if (t > 0) {
            const int target = 32 * t;   // 8 blocks x 4 publisher-waves per window
            int guard = 0;
            while (__hip_atomic_load(cntW, __ATOMIC_RELAXED, __HIP_MEMORY_SCOPE_AGENT) < target
                   && guard < (1 << 20)) {
                __builtin_amdgcn_s_sleep(1);
                ++guard;
            }
            __builtin_amdgcn_fence(__ATOMIC_ACQUIRE, "workgroup");  // no hoisting of P loads
        }

        // ===== phase A: msg = tanh(tanh(P_i + Q_j) @ Wm2 + bm2), A-weighted agg =====
        f32x4 acc[2][4];
        #pragma unroll
        for (int mt = 0; mt < 2; ++mt)
            #pragma unroll
            for (int nt = 0; nt < 4; ++nt) {
                f32x4 z = {0.f, 0.f, 0.f, 0.f};
                acc[mt][nt] = z;
            }
        #pragma unroll
        for (int kt = 0; kt < 4; ++kt) {
            int k0 = kt * 32 + g * 8;
            bf16x8 bf[4];
            #pragma unroll
            for (int nt = 0; nt < 4; ++nt)
                bf[nt] = *(const bf16x8*)&wm2f[((kt * 4 + nt) * 64 + lane) << 3];
            f32x4 qa = *(const f32x4*)&Qj[jj][k0];
            f32x4 qb = *(const f32x4*)&Qj[jj][k0 + 4];
            bf16x8 af[2];
            #pragma unroll
            for (int mt = 0; mt < 2; ++mt) {
                int row = myI0 + mt * 16 + l15;
                float pe[8];
                if (t > 0) {    // direct 16B load from the fresh per-step buffer
                    u32x4 pv = *(const u32x4*)(Psrc + row * 64 + kt * 16 + g * 4);
                    #pragma unroll
                    for (int c = 0; c < 4; ++c) {
                        pe[2 * c]     = __builtin_bit_cast(float, pv[c] << 16);
                        pe[2 * c + 1] = __builtin_bit_cast(float, pv[c] & 0xFFFF0000u);
                    }
                } else {        // P(0) rows are all bm1 (h0 = 0)
                    #pragma unroll
                    for (int e = 0; e < 8; ++e) pe[e] = bmS[k0 + e];
                }
                float tv[8];
                #pragma unroll
                for (int e = 0; e < 4; ++e) {
                    tv[e]     = fast_tanh(pe[e] + qa[e]);
                    tv[4 + e] = fast_tanh(pe[4 + e] + qb[e]);
                }
                u32x4 aw;
                aw[0] = cvtpk(tv[0], tv[1]); aw[1] = cvtpk(tv[2], tv[3]);
                aw[2] = cvtpk(tv[4], tv[5]); aw[3] = cvtpk(tv[6], tv[7]);
                af[mt] = __builtin_bit_cast(bf16x8, aw);
            }
            #pragma unroll
            for (int mt = 0; mt < 2; ++mt)
                #pragma unroll
                for (int nt = 0; nt < 4; ++nt)
                    acc[mt][nt] = __builtin_amdgcn_mfma_f32_16x16x32_bf16(af[mt], bf[nt], acc[mt][nt], 0, 0, 0);
        }
        {
            float bmv[4];
            #pragma unroll
            for (int nt = 0; nt < 4; ++nt) bmv[nt] = bm2[nt * 16 + l15];
            float pagg[4] = {0.f, 0.f, 0.f, 0.f};
            #pragma unroll
            for (int mt = 0; mt < 2; ++mt) {
                float w[4];
                #pragma unroll
                for (int v = 0; v < 4; ++v) w[v] = apRow[jj][myI0 + mt * 16 + g * 4 + v];
                #pragma unroll
                for (int nt = 0; nt < 4; ++nt)
                    #pragma unroll
                    for (int v = 0; v < 4; ++v)
                        pagg[nt] += w[v] * fast_tanh(acc[mt][nt][v] + bmv[nt]);
            }
            #pragma unroll
            for (int nt = 0; nt < 4; ++nt) {
                pagg[nt] += __shfl_xor(pagg[nt], 16);
                pagg[nt] += __shfl_xor(pagg[nt], 32);
            }
            if (lane < 16)
                #pragma unroll
                for (int nt = 0; nt < 4; ++nt) aggbuf[jj][wvj][nt * 16 + lane] = pagg[nt];
        }
        __syncthreads();
        if (tid < 256) {
            int r = tid >> 6, o = tid & 63;
            sAgg[r][o] = aggbuf[r][0][o] + aggbuf[r][1][o] + aggbuf[r][2][o] + aggbuf[r][3][o];
        }
        if (tid < 16) {
            int r = tid >> 2, d = tid & 3, jrow = j0 + r;
            sX[r][d]   = X[((b * 13 + t) * 128 + jrow) * 4 + d];
            sTgt[r][d] = X[((b * 13 + t + 1) * 128 + jrow) * 4 + d];
        }
        __syncthreads();

        // ===== phase B =====
        if (tid < 384) {   // am = agg @ [Wmr|Wmi|Wmn] from LDS, 2-row acc
            int pr = tid / 192, c = tid % 192;
            int r0 = pr * 2, r1 = r0 + 1;
            float a0 = 0.f, a1 = 0.f;
            #pragma unroll 8
            for (int k = 0; k < 64; ++k) {
                float w = WamL[k * 192 + c];
                a0 += sAgg[r0][k] * w; a1 += sAgg[r1][k] * w;
            }
            sAm[r0][c] = a0; sAm[r1][c] = a1;
        }
        __syncthreads();
        if (tid < 256) {   // GRU gates, one row per 64-thread group
            int r = tid >> 6, o = tid & 63;
            float xr = bir[o], xi = bii[o], xn = bin_[o];
            #pragma unroll
            for (int d = 0; d < 4; ++d) {
                float xv = sX[r][d];
                xr += xv * Wir[d * 64 + o];
                xi += xv * Wii[d * 64 + o];
                xn += xv * Win[d * 64 + o];
            }
            float rr = fast_sigmoid(xr + sHP[r][o]       + sAm[r][o]);
            float ig = fast_sigmoid(xi + sHP[r][64 + o]  + sAm[r][64 + o]);
            float nn = fast_tanh  (xn + rr * sHP[r][128 + o] + sAm[r][128 + o]);
            float hn = (1.0f - ig) * nn + ig * sH[r][o];
            sHn[r][o] = hn; sH[r][o] = hn;
        }
        __syncthreads();

        // parallel GEMV group: P'(publish) / Q' / HP' / Wo1 on disjoint waves
        const bool lastT = (t == TSTEPS - 1);
        if (tid < 128 || (tid >= 512 && tid < 640)) {          // P' + publish + signal
            if (!lastT) {
                int hi2 = (tid >= 512) ? 1 : 0;
                int o = tid - hi2 * 512;            // 0..127
                int r0 = hi2 * 2, r1 = r0 + 1;
                float a0 = bmS[o], a1 = bmS[o];
                #pragma unroll 8
                for (int k = 0; k < 64; ++k) {
                    float w = Wm1L[k * 128 + o];
                    a0 += sHn[r0][k] * w; a1 += sHn[r1][k] * w;
                }
                uint32 u0 = cvtpk(a0, __shfl_down(a0, 1));
                uint32 u1 = cvtpk(a1, __shfl_down(a1, 1));
                if ((o & 1) == 0) {
                    uint32* base = wsU + t * PB_STRIDE + b * 8192;
                    __hip_atomic_store(base + (j0 + r0) * 64 + (o >> 1), u0,
                                       __ATOMIC_RELAXED, __HIP_MEMORY_SCOPE_AGENT);
                    __hip_atomic_store(base + (j0 + r1) * 64 + (o >> 1), u1,
                                       __ATOMIC_RELAXED, __HIP_MEMORY_SCOPE_AGENT);
                }
                asm volatile("s_waitcnt vmcnt(0)" ::: "memory");   // wave's stores landed
                if (lane == 0)
                    __hip_atomic_fetch_add(cntPub, 1, __ATOMIC_RELAXED, __HIP_MEMORY_SCOPE_AGENT);
            }
        } else if (tid < 256 || (tid >= 640 && tid < 768)) {   // Q' (local, LDS weights)
            if (!lastT) {
                int hi2 = (tid >= 640) ? 1 : 0;
                int oo = tid - 128 - hi2 * 512;
                int r0 = hi2 * 2, r1 = r0 + 1;
                float a0 = 0.f, a1 = 0.f;
                #pragma unroll 8
                for (int k = 0; k < 64; ++k) {
                    float w = Wm1L[(64 + k) * 128 + oo];
                    a0 += sHn[r0][k] * w; a1 += sHn[r1][k] * w;
                }
                Qj[r0][oo] = a0; Qj[r1][oo] = a1;
            }
        } else if (tid < 448 || (tid >= 768 && tid < 960)) {   // HP' (global weights)
            if (!lastT) {
                int hi2 = (tid >= 768) ? 1 : 0;
                int c = tid - 256 - hi2 * 512;      // 0..191
                int r0 = hi2 * 2, r1 = r0 + 1;
                const float* W = (c < 64) ? Whr : (c < 128) ? Whi : Whh;
                int oc = c & 63;
                float a0 = 0.f, a1 = 0.f;
                #pragma unroll 8
                for (int k = 0; k < 64; ++k) {
                    float w = W[k * 64 + oc];
                    a0 += sHn[r0][k] * w; a1 += sHn[r1][k] * w;
                }
                sHP[r0][c] = a0; sHP[r1][c] = a1;
            }
        } else {                                               // Wo1 (always)
            int hi2 = (tid >= 960) ? 1 : 0;
            int o = tid - 448 - hi2 * 512;          // 0..63
            int r0 = hi2 * 2, r1 = r0 + 1;
            float a0 = bo1[o], a1 = a0;
            #pragma unroll 8
            for (int k = 0; k < 64; ++k) {
                float w = Wo1[k * 64 + o];
                a0 += sHn[r0][k] * w; a1 += sHn[r1][k] * w;
            }
            sT1[r0][o] = fmaxf(a0, 0.f); sT1[r1][o] = fmaxf(a1, 0.f);
        }
        __syncthreads();
        if (tid < 256) {   // Wo2, one row per 64-thread group
            int r = tid >> 6, o = tid & 63;
            float a = bo2[o];
            #pragma unroll 8
            for (int k = 0; k < 64; ++k) a += sT1[r][k] * Wo2[k * 64 + o];
            sT2[r][o] = fmaxf(a, 0.f);
        }
        __syncthreads();
        if (tid < 64) {    // Wo3: 4 threads per (r,d), shfl-reduce
            int r = tid >> 4, d = (tid >> 2) & 3, q = tid & 3;
            float a = 0.f;
            #pragma unroll 4
            for (int k = q * 16; k < q * 16 + 16; ++k) a += sT2[r][k] * Wo3[k * 4 + d];
            a += __shfl_xor(a, 1);
            a += __shfl_xor(a, 2);
            if (q == 0) {
                float p = sX[r][d] + a + bo3[d];
                out[((b * TSTEPS + t) * 128 + (j0 + r)) * 4 + d] = p;
                float df = sTgt[r][d] - p;
                sSq[r][d] = df * df;
            }
        }
        __syncthreads();
        if (tid == 0) {
            float s = 0.f;
            #pragma unroll
            for (int r = 0; r < 4; ++r)
                #pragma unroll
                for (int d = 0; d < 4; ++d) s += sSq[r][d];
            sseb[0] += s;
        }
        __syncthreads();
    }

    // ================= finalize loglik (last-arriver) =================
    if (tid == 0) atomicAdd(sseG, sseb[0]);
    __syncthreads();   // drain the SSE atomic before DONE
    if (tid == 0) {
        int prev = __hip_atomic_fetch_add(doneG, 1, __ATOMIC_RELAXED, __HIP_MEMORY_SCOPE_AGENT);
        if (prev == NBLK - 1) {
            float sse = __hip_atomic_load(sseG, __ATOMIC_RELAXED, __HIP_MEMORY_SCOPE_AGENT);
            float ls = lsg[0];
            float sigma = fminf(fmaxf(expf(ls), 1e-4f), 10.0f);
            float c = 0.5f * 4096.0f * logf(2.0f * 3.14159265358979323846f * sigma * sigma);
            float inv2s2 = 1.0f / (2.0f * sigma * sigma);
            out[B_ * TSTEPS * N_ * D_] = -(12.0f * c + sse * inv2s2);
        }
    }
}

extern "C" void kernel_launch(void* const* d_in, const int* in_sizes, int n_in,
                              void* d_out, int out_size, void* d_ws, size_t ws_size,
                              hipStream_t stream)
{
    const float* A    = (const float*)d_in[0];
    const float* X    = (const float*)d_in[1];
    const float* Wm1  = (const float*)d_in[2];
    const float* bm1  = (const float*)d_in[3];
    const float* Wm2  = (const float*)d_in[4];
    const float* bm2  = (const float*)d_in[5];
    const float* Wir  = (const float*)d_in[6];
    const float* bir  = (const float*)d_in[7];
    const float* Wii  = (const float*)d_in[8];
    const float* bii  = (const float*)d_in[9];
    const float* Win  = (const float*)d_in[10];
    const float* bin_ = (const float*)d_in[11];
    const float* Whr  = (const float*)d_in[12];
    const float* Whi  = (const float*)d_in[13];
    const float* Whh  = (const float*)d_in[14];
    const float* Wmr  = (const float*)d_in[15];
    const float* Wmi  = (const float*)d_in[16];
    const float* Wmn  = (const float*)d_in[17];
    const float* Wo1  = (const float*)d_in[18];
    const float* bo1  = (const float*)d_in[19];
    const float* Wo2  = (const float*)d_in[20];
    const float* bo2  = (const float*)d_in[21];
    const float* Wo3  = (const float*)d_in[22];
    const float* bo3  = (const float*)d_in[23];
    const float* lsg  = (const float*)d_in[24];
    uint32* wsU = (uint32*)d_ws;
    float* out = (float*)d_out;

    // zero counters / SSE / DONE each call (graph-replay safe)
    hipMemsetAsync((char*)d_ws + (size_t)CTRLu * 4, 0, CTRL_BYTES, stream);

    hipLaunchKernelGGL(fused, dim3(NBLK), dim3(1024), 0, stream,
                       A, X, Wm1, bm1, Wm2, bm2, Wir, bir, Wii, bii, Win, bin_,
                       Whr, Whi, Whh, Wmr, Wmi, Wmn, Wo1, bo1, Wo2, bo2, Wo3, bo3,
                       lsg, wsU, out);
}

// Round 15
// 199.030 us; speedup vs baseline: 1.4152x; 1.1047x over previous
//
#include <hip/hip_runtime.h>
#include <math.h>

// Problem constants
#define B_ 8
#define N_ 128
#define H_ 64
#define MH_ 128
#define D_ 4
#define TSTEPS 12
#define NBLK 256          // 1 block/CU x 256 CU -> all co-resident

typedef __attribute__((ext_vector_type(8))) short bf16x8;
typedef __attribute__((ext_vector_type(4))) float f32x4;
typedef __attribute__((ext_vector_type(4))) unsigned u32x4;
typedef unsigned uint32;

__device__ __forceinline__ float fast_tanh(float x) {
    float t = __builtin_amdgcn_exp2f(x * 2.8853900817779268f);
    return 1.0f - 2.0f * __builtin_amdgcn_rcpf(t + 1.0f);
}
__device__ __forceinline__ float fast_sigmoid(float x) {
    float t = __builtin_amdgcn_exp2f(x * -1.4426950408889634f);
    return __builtin_amdgcn_rcpf(1.0f + t);
}
__device__ __forceinline__ unsigned short f2bf(float x) {
    unsigned u = __builtin_bit_cast(unsigned, x);
    u += 0x7fffu + ((u >> 16) & 1u);   // RNE
    return (unsigned short)(u >> 16);
}
// packed bf16 pair: low16 = bf16(lo), high16 = bf16(hi); RNE (same as f2bf)
__device__ __forceinline__ uint32 cvtpk(float lo, float hi) {
    uint32 r;
    asm("v_cvt_pk_bf16_f32 %0, %1, %2" : "=v"(r) : "v"(lo), "v"(hi));
    return r;
}

// ---------------- workspace layout (uint32 units) ----------------
// P(t+1) in its own per-step buffer (t = 0..10): consumer addresses are first
// touched only after the producer's write-through lands -> plain coalesced
// loads are fresh, no fences. Producers publish via relaxed agent-scope
// (write-through) atomic stores. Sync per (batch, 32-row i-window).
constexpr int PB_STRIDE = 65536;              // [8][128][64] uints per step-buffer
constexpr int CTRLu = 11 * PB_STRIDE;         // cnt[8][4] @ stride 16; SSE @ +512; DONE @ +513
constexpr int CTRL_BYTES = (32 * 16 + 2) * 4;

__global__ __launch_bounds__(1024, 4) void fused(
    const float* __restrict__ A, const float* __restrict__ X,
    const float* __restrict__ Wm1, const float* __restrict__ bm1,
    const float* __restrict__ Wm2, const float* __restrict__ bm2,
    const float* __restrict__ Wir, const float* __restrict__ bir,
    const float* __restrict__ Wii, const float* __restrict__ bii,
    const float* __restrict__ Win, const float* __restrict__ bin_,
    const float* __restrict__ Whr, const float* __restrict__ Whi, const float* __restrict__ Whh,
    const float* __restrict__ Wmr, const float* __restrict__ Wmi, const float* __restrict__ Wmn,
    const float* __restrict__ Wo1, const float* __restrict__ bo1,
    const float* __restrict__ Wo2, const float* __restrict__ bo2,
    const float* __restrict__ Wo3, const float* __restrict__ bo3,
    const float* __restrict__ lsg,
    uint32* wsU, float* __restrict__ out)
{
    __shared__ __align__(16) unsigned short wm2f[8192];  // 16 KB Wm2 MFMA B-fragments
    __shared__ __align__(16) float WamL[12288];          // 48 KB [k][192] Wmr|Wmi|Wmn
    __shared__ __align__(16) float Wm1L[16384];          // 64 KB [k][128] (full Wm1)
    __shared__ float Qj[4][128], apRow[4][128], rs[128], bmS[128];
    __shared__ float aggbuf[4][4][64];                   // rowsum partials / agg partials / MLP scratch
    __shared__ float sAgg[4][64], sAm[4][192], sHP[4][192];
    __shared__ float sHist[TSTEPS][4][64];               // 12 KB: h(t) history
    __shared__ float sX[4][4];

    const int bid = blockIdx.x, tid = threadIdx.x;
    const int b = bid >> 5;                 // batch
    const int j0 = (bid & 31) << 2;         // block owns rows j0..j0+3
    const int wave = tid >> 6, lane = tid & 63;
    const int jj = wave >> 2;               // which of the 4 j-rows (phase A)
    const int wvj = wave & 3;               // i-window index (phase A)
    const int l15 = lane & 15, g = lane >> 4;
    const int myI0 = wvj * 32;

    int*   cntBase = (int*)(wsU + CTRLu);
    int*   cntW    = cntBase + (b * 4 + wvj) * 16;          // window this wave CONSUMES
    int*   cntPub  = cntBase + (b * 4 + (j0 >> 5)) * 16;    // window this block PRODUCES
    float* sseG    = (float*)(wsU + CTRLu + 512);
    int*   doneG   = (int*)(wsU + CTRLu + 513);
    const float* Ab = A + b * 16384;

    // ================= init (fully block-local) =================
    {   // rowsum_i: 1024 threads, 8 chunks of 16 j each
        int i = tid & 127, q = tid >> 7;
        float part = 0.f;
        int jlo = q * 16;
        #pragma unroll 4
        for (int j2 = jlo; j2 < jlo + 16; ++j2)
            if (j2 != i)
                part += fast_sigmoid(0.5f * (Ab[i * 128 + j2] + Ab[j2 * 128 + i]));
        ((float*)aggbuf)[q * 128 + i] = part;   // [8][128] view (1024 floats)
    }
    __syncthreads();
    if (tid < 128) {
        const float* f = (const float*)aggbuf;
        float s = 0.f;
        #pragma unroll
        for (int c = 0; c < 8; ++c) s += f[c * 128 + tid];
        rs[tid] = s + 1e-6f;
        bmS[tid] = bm1[tid];
    }
    __syncthreads();
    if (tid < 512) {    // apRow[h][i] = s(i, j0+h) / rowsum_i
        int i = tid & 127, h = tid >> 7, jc = j0 + h;
        float s = (i == jc) ? 0.f
                : fast_sigmoid(0.5f * (Ab[i * 128 + jc] + Ab[jc * 128 + i]));
        apRow[h][i] = s / rs[i];
    }
    for (int idx = tid; idx < 8192; idx += 1024) {   // pack Wm2 -> bf16 B-fragments
        int kt = idx >> 11, nt = (idx >> 9) & 3, ln = (idx >> 3) & 63, e = idx & 7;
        int k = kt * 32 + (ln >> 4) * 8 + e, n = nt * 16 + (ln & 15);
        wm2f[idx] = f2bf(Wm2[k * 64 + n]);
    }
    for (int idx = tid; idx < 12288; idx += 1024) {  // WamL[k*192+c] fp32
        int k = idx / 192, c = idx % 192;
        WamL[idx] = ((c < 64) ? Wmr : (c < 128) ? Wmi : Wmn)[k * 64 + (c & 63)];
    }
    for (int idx = tid; idx < 16384; idx += 1024)    // Wm1L direct copy [128][128]
        Wm1L[idx] = Wm1[idx];
    if (tid < 512) Qj[tid >> 7][tid & 127] = 0.f;
    if (tid < 768) sHP[tid / 192][tid % 192] = 0.f;
    __syncthreads();

    // ================= time loop =================
    for (int t = 0; t < TSTEPS; ++t) {
        const uint32* Psrc = wsU + (t - 1) * PB_STRIDE + b * 8192;  // valid for t>0
        if (t > 0) {
            const int target = 32 * t;   // 8 blocks x 4 publisher-waves per window
            int guard = 0;
            while (__hip_atomic_load(cntW, __ATOMIC_RELAXED, __HIP_MEMORY_SCOPE_AGENT) < target
                   && guard < (1 << 20)) {
                __builtin_amdgcn_s_sleep(1);
                ++guard;
            }
            __builtin_amdgcn_fence(__ATOMIC_ACQUIRE, "workgroup");  // no hoisting of P loads
        }

        // ===== phase A: msg = tanh(tanh(P_i + Q_j) @ Wm2 + bm2), A-weighted agg =====
        f32x4 acc[2][4];
        #pragma unroll
        for (int mt = 0; mt < 2; ++mt)
            #pragma unroll
            for (int nt = 0; nt < 4; ++nt) {
                f32x4 z = {0.f, 0.f, 0.f, 0.f};
                acc[mt][nt] = z;
            }
        #pragma unroll
        for (int kt = 0; kt < 4; ++kt) {
            int k0 = kt * 32 + g * 8;
            bf16x8 bf[4];
            #pragma unroll
            for (int nt = 0; nt < 4; ++nt)
                bf[nt] = *(const bf16x8*)&wm2f[((kt * 4 + nt) * 64 + lane) << 3];
            f32x4 qa = *(const f32x4*)&Qj[jj][k0];
            f32x4 qb = *(const f32x4*)&Qj[jj][k0 + 4];
            bf16x8 af[2];
            #pragma unroll
            for (int mt = 0; mt < 2; ++mt) {
                int row = myI0 + mt * 16 + l15;
                float pe[8];
                if (t > 0) {    // direct 16B load from the fresh per-step buffer
                    u32x4 pv = *(const u32x4*)(Psrc + row * 64 + kt * 16 + g * 4);
                    #pragma unroll
                    for (int c = 0; c < 4; ++c) {
                        pe[2 * c]     = __builtin_bit_cast(float, pv[c] << 16);
                        pe[2 * c + 1] = __builtin_bit_cast(float, pv[c] & 0xFFFF0000u);
                    }
                } else {        // P(0) rows are all bm1 (h0 = 0)
                    #pragma unroll
                    for (int e = 0; e < 8; ++e) pe[e] = bmS[k0 + e];
                }
                float tv[8];
                #pragma unroll
                for (int e = 0; e < 4; ++e) {
                    tv[e]     = fast_tanh(pe[e] + qa[e]);
                    tv[4 + e] = fast_tanh(pe[4 + e] + qb[e]);
                }
                u32x4 aw;
                aw[0] = cvtpk(tv[0], tv[1]); aw[1] = cvtpk(tv[2], tv[3]);
                aw[2] = cvtpk(tv[4], tv[5]); aw[3] = cvtpk(tv[6], tv[7]);
                af[mt] = __builtin_bit_cast(bf16x8, aw);
            }
            #pragma unroll
            for (int mt = 0; mt < 2; ++mt)
                #pragma unroll
                for (int nt = 0; nt < 4; ++nt)
                    acc[mt][nt] = __builtin_amdgcn_mfma_f32_16x16x32_bf16(af[mt], bf[nt], acc[mt][nt], 0, 0, 0);
        }
        {
            float bmv[4];
            #pragma unroll
            for (int nt = 0; nt < 4; ++nt) bmv[nt] = bm2[nt * 16 + l15];
            float pagg[4] = {0.f, 0.f, 0.f, 0.f};
            #pragma unroll
            for (int mt = 0; mt < 2; ++mt) {
                float w[4];
                #pragma unroll
                for (int v = 0; v < 4; ++v) w[v] = apRow[jj][myI0 + mt * 16 + g * 4 + v];
                #pragma unroll
                for (int nt = 0; nt < 4; ++nt)
                    #pragma unroll
                    for (int v = 0; v < 4; ++v)
                        pagg[nt] += w[v] * fast_tanh(acc[mt][nt][v] + bmv[nt]);
            }
            #pragma unroll
            for (int nt = 0; nt < 4; ++nt) {
                pagg[nt] += __shfl_xor(pagg[nt], 16);
                pagg[nt] += __shfl_xor(pagg[nt], 32);
            }
            if (lane < 16)
                #pragma unroll
                for (int nt = 0; nt < 4; ++nt) aggbuf[jj][wvj][nt * 16 + lane] = pagg[nt];
        }
        __syncthreads();
        if (tid < 256) {
            int r = tid >> 6, o = tid & 63;
            sAgg[r][o] = aggbuf[r][0][o] + aggbuf[r][1][o] + aggbuf[r][2][o] + aggbuf[r][3][o];
        }
        if (tid < 16) {
            int r = tid >> 2, d = tid & 3, jrow = j0 + r;
            sX[r][d] = X[((b * 13 + t) * 128 + jrow) * 4 + d];
        }
        __syncthreads();

        // ===== phase B =====
        if (tid < 384) {   // am = agg @ [Wmr|Wmi|Wmn] from LDS, 2-row acc
            int pr = tid / 192, c = tid % 192;
            int r0 = pr * 2, r1 = r0 + 1;
            float a0 = 0.f, a1 = 0.f;
            #pragma unroll 8
            for (int k = 0; k < 64; ++k) {
                float w = WamL[k * 192 + c];
                a0 += sAgg[r0][k] * w; a1 += sAgg[r1][k] * w;
            }
            sAm[r0][c] = a0; sAm[r1][c] = a1;
        }
        __syncthreads();
        if (tid < 256) {   // GRU gates, one row per 64-thread group; h -> history
            int r = tid >> 6, o = tid & 63;
            float xr = bir[o], xi = bii[o], xn = bin_[o];
            #pragma unroll
            for (int d = 0; d < 4; ++d) {
                float xv = sX[r][d];
                xr += xv * Wir[d * 64 + o];
                xi += xv * Wii[d * 64 + o];
                xn += xv * Win[d * 64 + o];
            }
            float hprev = (t > 0) ? sHist[t - 1][r][o] : 0.f;
            float rr = fast_sigmoid(xr + sHP[r][o]       + sAm[r][o]);
            float ig = fast_sigmoid(xi + sHP[r][64 + o]  + sAm[r][64 + o]);
            float nn = fast_tanh  (xn + rr * sHP[r][128 + o] + sAm[r][128 + o]);
            sHist[t][r][o] = (1.0f - ig) * nn + ig * hprev;
        }
        __syncthreads();

        // parallel GEMV group: P'(publish) / Q' / HP' on disjoint waves
        if (t < TSTEPS - 1) {
            if (tid < 128 || (tid >= 512 && tid < 640)) {          // P' + publish + signal
                int hi2 = (tid >= 512) ? 1 : 0;
                int o = tid - hi2 * 512;            // 0..127
                int r0 = hi2 * 2, r1 = r0 + 1;
                float a0 = bmS[o], a1 = bmS[o];
                #pragma unroll 8
                for (int k = 0; k < 64; ++k) {
                    float w = Wm1L[k * 128 + o];
                    a0 += sHist[t][r0][k] * w; a1 += sHist[t][r1][k] * w;
                }
                uint32 u0 = cvtpk(a0, __shfl_down(a0, 1));
                uint32 u1 = cvtpk(a1, __shfl_down(a1, 1));
                if ((o & 1) == 0) {
                    uint32* base = wsU + t * PB_STRIDE + b * 8192;
                    __hip_atomic_store(base + (j0 + r0) * 64 + (o >> 1), u0,
                                       __ATOMIC_RELAXED, __HIP_MEMORY_SCOPE_AGENT);
                    __hip_atomic_store(base + (j0 + r1) * 64 + (o >> 1), u1,
                                       __ATOMIC_RELAXED, __HIP_MEMORY_SCOPE_AGENT);
                }
                asm volatile("s_waitcnt vmcnt(0)" ::: "memory");   // wave's stores landed
                if (lane == 0)
                    __hip_atomic_fetch_add(cntPub, 1, __ATOMIC_RELAXED, __HIP_MEMORY_SCOPE_AGENT);
            } else if (tid < 256 || (tid >= 640 && tid < 768)) {   // Q' (local, LDS weights)
                int hi2 = (tid >= 640) ? 1 : 0;
                int oo = tid - 128 - hi2 * 512;
                int r0 = hi2 * 2, r1 = r0 + 1;
                float a0 = 0.f, a1 = 0.f;
                #pragma unroll 8
                for (int k = 0; k < 64; ++k) {
                    float w = Wm1L[(64 + k) * 128 + oo];
                    a0 += sHist[t][r0][k] * w; a1 += sHist[t][r1][k] * w;
                }
                Qj[r0][oo] = a0; Qj[r1][oo] = a1;
            } else if (tid < 448 || (tid >= 768 && tid < 960)) {   // HP' (global weights)
                int hi2 = (tid >= 768) ? 1 : 0;
                int c = tid - 256 - hi2 * 512;      // 0..191
                int r0 = hi2 * 2, r1 = r0 + 1;
                const float* W = (c < 64) ? Whr : (c < 128) ? Whi : Whh;
                int oc = c & 63;
                float a0 = 0.f, a1 = 0.f;
                #pragma unroll 8
                for (int k = 0; k < 64; ++k) {
                    float w = W[k * 64 + oc];
                    a0 += sHist[t][r0][k] * w; a1 += sHist[t][r1][k] * w;
                }
                sHP[r0][c] = a0; sHP[r1][c] = a1;
            }
        }
        __syncthreads();
    }

    // ================= deferred output MLP + SSE (off the recurrence path) =================
    float ssePart = 0.f;
    {
        float* scratch = &((float*)aggbuf)[wave * 64];   // [16][64] per-wave view
        #pragma unroll
        for (int inst = 0; inst < 3; ++inst) {
            int idx = wave + (inst << 4);      // 0..47 = (t, r)
            int tt = idx >> 2, r = idx & 3;
            // layer 1
            float a = bo1[lane];
            #pragma unroll 8
            for (int k = 0; k < 64; ++k) a += sHist[tt][r][k] * Wo1[k * 64 + lane];
            scratch[lane] = fmaxf(a, 0.f);
            asm volatile("s_waitcnt lgkmcnt(0)" ::: "memory");
            __builtin_amdgcn_sched_barrier(0);
            // layer 2
            float a2 = bo2[lane];
            #pragma unroll 8
            for (int k = 0; k < 64; ++k) a2 += scratch[k] * Wo2[k * 64 + lane];
            scratch[lane] = fmaxf(a2, 0.f);    // same-wave in-order LDS: reads precede write
            asm volatile("s_waitcnt lgkmcnt(0)" ::: "memory");
            __builtin_amdgcn_sched_barrier(0);
            // layer 3 + residual + SSE
            if (lane < 16) {
                int d = lane >> 2, q = lane & 3;
                float a3 = 0.f;
                #pragma unroll 4
                for (int k = q * 16; k < q * 16 + 16; ++k) a3 += scratch[k] * Wo3[k * 4 + d];
                a3 += __shfl_xor(a3, 1);
                a3 += __shfl_xor(a3, 2);
                if (q == 0) {
                    int jrow = j0 + r;
                    float xv = X[((b * 13 + tt) * 128 + jrow) * 4 + d];
                    float tg = X[((b * 13 + tt + 1) * 128 + jrow) * 4 + d];
                    float p = xv + a3 + bo3[d];
                    out[((b * TSTEPS + tt) * 128 + jrow) * 4 + d] = p;
                    float df = tg - p;
                    ssePart += df * df;
                }
            }
            asm volatile("s_waitcnt lgkmcnt(0)" ::: "memory");   // reads done before next overwrite
            __builtin_amdgcn_sched_barrier(0);
        }
    }
    #pragma unroll
    for (int d = 1; d < 64; d <<= 1) ssePart += __shfl_xor(ssePart, d);
    if (lane == 0) rs[wave] = ssePart;
    __syncthreads();

    // ================= finalize loglik (last-arriver) =================
    if (tid == 0) {
        float s = 0.f;
        #pragma unroll
        for (int w = 0; w < 16; ++w) s += rs[w];
        atomicAdd(sseG, s);
        int prev = __hip_atomic_fetch_add(doneG, 1, __ATOMIC_ACQ_REL, __HIP_MEMORY_SCOPE_AGENT);
        if (prev == NBLK - 1) {
            float sse = __hip_atomic_load(sseG, __ATOMIC_RELAXED, __HIP_MEMORY_SCOPE_AGENT);
            float ls = lsg[0];
            float sigma = fminf(fmaxf(expf(ls), 1e-4f), 10.0f);
            float c = 0.5f * 4096.0f * logf(2.0f * 3.14159265358979323846f * sigma * sigma);
            float inv2s2 = 1.0f / (2.0f * sigma * sigma);
            out[B_ * TSTEPS * N_ * D_] = -(12.0f * c + sse * inv2s2);
        }
    }
}

extern "C" void kernel_launch(void* const* d_in, const int* in_sizes, int n_in,
                              void* d_out, int out_size, void* d_ws, size_t ws_size,
                              hipStream_t stream)
{
    const float* A    = (const float*)d_in[0];
    const float* X    = (const float*)d_in[1];
    const float* Wm1  = (const float*)d_in[2];
    const float* bm1  = (const float*)d_in[3];
    const float* Wm2  = (const float*)d_in[4];
    const float* bm2  = (const float*)d_in[5];
    const float* Wir  = (const float*)d_in[6];
    const float* bir  = (const float*)d_in[7];
    const float* Wii  = (const float*)d_in[8];
    const float* bii  = (const float*)d_in[9];
    const float* Win  = (const float*)d_in[10];
    const float* bin_ = (const float*)d_in[11];
    const float* Whr  = (const float*)d_in[12];
    const float* Whi  = (const float*)d_in[13];
    const float* Whh  = (const float*)d_in[14];
    const float* Wmr  = (const float*)d_in[15];
    const float* Wmi  = (const float*)d_in[16];
    const float* Wmn  = (const float*)d_in[17];
    const float* Wo1  = (const float*)d_in[18];
    const float* bo1  = (const float*)d_in[19];
    const float* Wo2  = (const float*)d_in[20];
    const float* bo2  = (const float*)d_in[21];
    const float* Wo3  = (const float*)d_in[22];
    const float* bo3  = (const float*)d_in[23];
    const float* lsg  = (const float*)d_in[24];
    uint32* wsU = (uint32*)d_ws;
    float* out = (float*)d_out;

    // zero counters / SSE / DONE each call (graph-replay safe)
    hipMemsetAsync((char*)d_ws + (size_t)CTRLu * 4, 0, CTRL_BYTES, stream);

    hipLaunchKernelGGL(fused, dim3(NBLK), dim3(1024), 0, stream,
                       A, X, Wm1, bm1, Wm2, bm2, Wir, bir, Wii, bii, Win, bin_,
                       Whr, Whi, Whh, Wmr, Wmi, Wmn, Wo1, bo1, Wo2, bo2, Wo3, bo3,
                       lsg, wsU, out);
}